// Round 7
// baseline (183.022 us; speedup 1.0000x reference)
//
#include <hip/hip_runtime.h>

#define SEQ  4096
#define DMODEL 1024
#define QTOT 16384           // B*S
#define QSCALE 0.18033688011112042f   // (1/sqrt(64)) * log2(e), folded into Q

typedef __bf16 bf16x8 __attribute__((ext_vector_type(8)));
typedef unsigned short u16x8 __attribute__((ext_vector_type(8)));
typedef float f32x4 __attribute__((ext_vector_type(4)));
typedef float f32x16 __attribute__((ext_vector_type(16)));
typedef unsigned int u32x4 __attribute__((ext_vector_type(4)));

// ---------- helpers ----------
static __device__ __forceinline__ unsigned short f2bfbits(float f) {
    unsigned int u = __builtin_bit_cast(unsigned int, f);
    unsigned int lsb = (u >> 16) & 1u;
    u += 0x7fffu + lsb;                      // round-to-nearest-even
    return (unsigned short)(u >> 16);
}

static __device__ __forceinline__ bf16x8 ld_frag(const unsigned short* p) {
    uint4 u = *reinterpret_cast<const uint4*>(p);
    return __builtin_bit_cast(bf16x8, u);
}

static __device__ __forceinline__ unsigned cvtpk(float a, float b) {
    unsigned r;
    asm("v_cvt_pk_bf16_f32 %0, %1, %2" : "=v"(r) : "v"(a), "v"(b));
    return r;
}

// ---------- kernel 1: weights -> bf16, pre-swizzled into MFMA fragment order ----------
__global__ void prep_weights(const float* __restrict__ Wq,
                             const float* __restrict__ Wk,
                             const float* __restrict__ Wv,
                             unsigned short* __restrict__ WtS) {
    int o = blockIdx.x * 256 + threadIdx.x;      // 192*1024 total
    int f = o >> 9, q = o & 511;
    int lane = q >> 3, j = q & 7;
    int kc = f / 12, nt = f - kc * 12;
    int n = nt * 16 + (lane & 15);
    int k = kc * 32 + (lane >> 4) * 8 + j;
    float v;
    if (n < 64)       v = Wq[k * 64 + n];
    else if (n < 128) v = Wk[k * 64 + (n - 64)];
    else              v = Wv[k * 64 + (n - 128)];
    WtS[o] = f2bfbits(v);
}

// ---------- kernel 2: QKV projection, coalesced LDS-staged emb ----------
// (unchanged from round 3 — verified, no longer the top dispatch)
__global__ __launch_bounds__(256) void proj_cs(
        const float* __restrict__ emb, const unsigned short* __restrict__ WtS,
        const float* __restrict__ bq, const float* __restrict__ bk,
        const float* __restrict__ bv,
        unsigned short* __restrict__ Qb, unsigned short* __restrict__ Kb,
        unsigned short* __restrict__ VT) {
    __shared__ __align__(16) unsigned short Et[2][32 * 256];   // 2 x 16 KB

    const int tid = threadIdx.x;
    const int w = tid >> 6, lane = tid & 63;
    const int c = lane & 15, qd = lane >> 4;
    const int m = w & 1, nh = w >> 1;
    const int mbase = blockIdx.x * 32;

    f32x4 acc[6];
#pragma unroll
    for (int i = 0; i < 6; i++) acc[i] = (f32x4){0.f, 0.f, 0.f, 0.f};

    const unsigned short* wpB = WtS + nh * 3072 + lane * 8;

    {
        float4 g[8];
#pragma unroll
        for (int rr = 0; rr < 8; rr++)
            g[rr] = *reinterpret_cast<const float4*>(
                emb + (size_t)(mbase + w * 8 + rr) * DMODEL + lane * 4);
#pragma unroll
        for (int rr = 0; rr < 8; rr++) {
            int row = w * 8 + rr;
            ushort4 p;
            p.x = f2bfbits(g[rr].x); p.y = f2bfbits(g[rr].y);
            p.z = f2bfbits(g[rr].z); p.w = f2bfbits(g[rr].w);
            int off = (lane * 8) ^ ((row & 7) << 4);           // byte off in 512B row
            *reinterpret_cast<ushort4*>(
                reinterpret_cast<char*>(&Et[0][0]) + row * 512 + off) = p;
        }
    }

    bf16x8 wc[6];
#pragma unroll
    for (int jj = 0; jj < 6; jj++) wc[jj] = ld_frag(wpB + jj * 512);

    __syncthreads();

    int cur = 0;
    for (int mega = 0; mega < 4; mega++) {
        float4 g[8];
        if (mega < 3) {
#pragma unroll
            for (int rr = 0; rr < 8; rr++)
                g[rr] = *reinterpret_cast<const float4*>(
                    emb + (size_t)(mbase + w * 8 + rr) * DMODEL
                        + (mega + 1) * 256 + lane * 4);
        }

        const char* Eb = reinterpret_cast<const char*>(&Et[cur][0]);
        bf16x8 aq[8];
#pragma unroll
        for (int ks = 0; ks < 8; ks++) {
            int off = (ks * 64 + qd * 16) ^ ((c & 7) << 4);
            aq[ks] = ld_frag(reinterpret_cast<const unsigned short*>(
                Eb + (m * 16 + c) * 512 + off));
        }

#pragma unroll
        for (int ks = 0; ks < 8; ks++) {
            int s = mega * 8 + ks;
            bf16x8 wn[6];
            if (s < 31) {
#pragma unroll
                for (int jj = 0; jj < 6; jj++)
                    wn[jj] = ld_frag(wpB + (s + 1) * 6144 + jj * 512);
            } else {
#pragma unroll
                for (int jj = 0; jj < 6; jj++) wn[jj] = wc[jj];
            }
#pragma unroll
            for (int jj = 0; jj < 6; jj++)
                acc[jj] = __builtin_amdgcn_mfma_f32_16x16x32_bf16(aq[ks], wc[jj], acc[jj], 0, 0, 0);
#pragma unroll
            for (int jj = 0; jj < 6; jj++) wc[jj] = wn[jj];
        }

        if (mega < 3) {
#pragma unroll
            for (int rr = 0; rr < 8; rr++) {
                int row = w * 8 + rr;
                ushort4 p;
                p.x = f2bfbits(g[rr].x); p.y = f2bfbits(g[rr].y);
                p.z = f2bfbits(g[rr].z); p.w = f2bfbits(g[rr].w);
                int off = (lane * 8) ^ ((row & 7) << 4);
                *reinterpret_cast<ushort4*>(
                    reinterpret_cast<char*>(&Et[cur ^ 1][0]) + row * 512 + off) = p;
            }
        }
        __syncthreads();
        cur ^= 1;
    }

#pragma unroll
    for (int jj = 0; jj < 6; jj++) {
        int n = (nh * 6 + jj) * 16 + c;
        float bias = (n < 64) ? bq[n] : (n < 128) ? bk[n - 64] : bv[n - 128];
        float fac = (n < 64) ? QSCALE : 1.0f;
#pragma unroll
        for (int r = 0; r < 4; r++) {
            int token = mbase + m * 16 + qd * 4 + r;
            unsigned short bits = f2bfbits((acc[jj][r] + bias) * fac);
            if (n < 64)        Qb[(size_t)token * 64 + n] = bits;
            else if (n < 128)  Kb[(size_t)token * 64 + (n - 64)] = bits;
            else {
                int bb = token >> 12, ss = token & 4095;
                VT[((size_t)bb * 64 + (n - 128)) * SEQ + ss] = bits;
            }
        }
    }
}

// ---------- kernel 3: LDS-free flash attention, 32x32 swapped-QK, t-split=4 ----------
// grid 512 x 256 thr (4 waves, NO LDS, NO barriers). Wave owns 32 q-rows x
// 1024-t chunk. blockIdx&7 -> XCD slot pins (b, tc&1); 4 waves of a block share
// the same (b,tc) K/V stream -> L1 dedup.
// Per 32-t iteration: swapped QK^T (mfma(K,Q) -> S^T, col=q) puts a q-row's
// t-values lane-local; exp2 in-reg; T12 pack: 8 v_cvt_pk_bf16_f32 +
// 4 v_permlane32_swap_b32 assemble PV A-fragments IN REGISTERS (no P LDS
// round-trip, no 64 scalar ds_writes, no tree-reduce). V B-frags contiguous
// from VT[v][t]; Q/K frags contiguous from row-major Qb/Kb.
// Layouts (verified m74/m101): C/D col=lane&31, row=(reg&3)+8*(reg>>2)+4*(lane>>5);
// A/B lane: row/col=lane&31, k=(lane>>5)*8+j.
__global__ __launch_bounds__(256) void attn32(
        const unsigned short* __restrict__ Qb, const unsigned short* __restrict__ Kb,
        const unsigned short* __restrict__ VT,
        float* __restrict__ accP, float* __restrict__ lsumP) {
    const int tid = threadIdx.x;
    const int w = tid >> 6, l = tid & 63;
    const int lo = l & 31, hi = l >> 5;

    const int s  = blockIdx.x & 7;
    const int b  = s >> 1;
    const int tc = (s & 1) | (((blockIdx.x >> 3) & 1) << 1);   // 0..3
    const int qi = ((blockIdx.x >> 4) << 2) | w;               // 0..127
    const int qbase = (b << 12) + qi * 32;                     // global q row
    const int tbase = tc * 1024;

    // Q B-fragments, 4 d-blocks of k=16 (held in regs for the whole kernel)
    const unsigned short* Qp = Qb + (size_t)(qbase + lo) * 64 + hi * 8;
    bf16x8 qf0 = ld_frag(Qp);
    bf16x8 qf1 = ld_frag(Qp + 16);
    bf16x8 qf2 = ld_frag(Qp + 32);
    bf16x8 qf3 = ld_frag(Qp + 48);

    f32x16 o0 = {}, o1 = {};       // O accumulator: v-cols 0-31 / 32-63
    float lsum = 0.f;

    const unsigned short* KbB = Kb + (size_t)(b << 12) * 64;
    const unsigned short* VbB = VT + ((size_t)(b * 64) << 12);

#pragma unroll 2
    for (int it = 0; it < 32; ++it) {
        const int t0 = tbase + it * 32;

        // K A-frags first; V after (QK's wait leaves V in flight -> hidden)
        const unsigned short* Kp = KbB + (size_t)(t0 + lo) * 64 + hi * 8;
        bf16x8 kf0 = ld_frag(Kp);
        bf16x8 kf1 = ld_frag(Kp + 16);
        bf16x8 kf2 = ld_frag(Kp + 32);
        bf16x8 kf3 = ld_frag(Kp + 48);
        const unsigned short* Vp = VbB + ((size_t)lo << 12) + t0 + hi * 8;
        bf16x8 vf00 = ld_frag(Vp);                       // vb0, t 0-15
        bf16x8 vf01 = ld_frag(Vp + 16);                  // vb0, t 16-31
        bf16x8 vf10 = ld_frag(Vp + (32 << 12));          // vb1, t 0-15
        bf16x8 vf11 = ld_frag(Vp + (32 << 12) + 16);     // vb1, t 16-31

        // S^T[t][q] = K · Q^T  (Q pre-scaled by QSCALE -> exp2 direct)
        f32x16 st = {};
        st = __builtin_amdgcn_mfma_f32_32x32x16_bf16(kf0, qf0, st, 0, 0, 0);
        st = __builtin_amdgcn_mfma_f32_32x32x16_bf16(kf1, qf1, st, 0, 0, 0);
        st = __builtin_amdgcn_mfma_f32_32x32x16_bf16(kf2, qf2, st, 0, 0, 0);
        st = __builtin_amdgcn_mfma_f32_32x32x16_bf16(kf3, qf3, st, 0, 0, 0);

#pragma unroll
        for (int i = 0; i < 16; i++) {
            st[i] = __builtin_amdgcn_exp2f(st[i]);
            lsum += st[i];
        }

        // T12 pack: P -> bf16 PV A-fragments in registers
        unsigned a0 = cvtpk(st[0], st[1]),  b0 = cvtpk(st[4], st[5]);
        unsigned c0 = cvtpk(st[2], st[3]),  d0 = cvtpk(st[6], st[7]);
        asm("v_permlane32_swap_b32 %0, %1" : "+v"(a0), "+v"(b0));
        asm("v_permlane32_swap_b32 %0, %1" : "+v"(c0), "+v"(d0));
        unsigned a1 = cvtpk(st[8],  st[9]),  b1 = cvtpk(st[12], st[13]);
        unsigned c1 = cvtpk(st[10], st[11]), d1 = cvtpk(st[14], st[15]);
        asm("v_permlane32_swap_b32 %0, %1" : "+v"(a1), "+v"(b1));
        asm("v_permlane32_swap_b32 %0, %1" : "+v"(c1), "+v"(d1));
        bf16x8 pa0 = __builtin_bit_cast(bf16x8, (u32x4){a0, c0, b0, d0});  // t 0-15
        bf16x8 pa1 = __builtin_bit_cast(bf16x8, (u32x4){a1, c1, b1, d1});  // t 16-31

        // O += P · V
        o0 = __builtin_amdgcn_mfma_f32_32x32x16_bf16(pa0, vf00, o0, 0, 0, 0);
        o0 = __builtin_amdgcn_mfma_f32_32x32x16_bf16(pa1, vf01, o0, 0, 0, 0);
        o1 = __builtin_amdgcn_mfma_f32_32x32x16_bf16(pa0, vf10, o1, 0, 0, 0);
        o1 = __builtin_amdgcn_mfma_f32_32x32x16_bf16(pa1, vf11, o1, 0, 0, 0);
    }

    // lane l and l+32 hold complementary t-halves of the same q=lo
    lsum += __shfl_xor(lsum, 32);
    if (hi == 0) lsumP[(size_t)tc * QTOT + qbase + lo] = lsum;

    float* accOut = accP + (size_t)tc * ((size_t)QTOT * 64);
#pragma unroll
    for (int r = 0; r < 16; r++) {
        int q = (r & 3) + ((r >> 2) << 3) + (hi << 2);
        accOut[(size_t)(qbase + q) * 64 + lo]      = o0[r];
        accOut[(size_t)(qbase + q) * 64 + 32 + lo] = o1[r];
    }
}

// ---------- kernel 4: merge the four t-quarters: out = Σa / Σl ----------
__global__ __launch_bounds__(256) void finalize(
        const float* __restrict__ accP, const float* __restrict__ lsumP,
        float* __restrict__ out) {
    int idx = blockIdx.x * 256 + threadIdx.x;    // float4 index, 0..QTOT*16-1
    int row = idx >> 4;
    float4 a = reinterpret_cast<const float4*>(accP)[idx];
    float lt = lsumP[row];
#pragma unroll
    for (int tcq = 1; tcq < 4; tcq++) {
        float4 ai = reinterpret_cast<const float4*>(accP)[idx + tcq * (QTOT * 16)];
        a.x += ai.x; a.y += ai.y; a.z += ai.z; a.w += ai.w;
        lt += lsumP[row + tcq * QTOT];
    }
    float inv = 1.0f / lt;
    float4 o;
    o.x = a.x * inv; o.y = a.y * inv; o.z = a.z * inv; o.w = a.w * inv;
    reinterpret_cast<float4*>(out)[idx] = o;
}

// ---------- launch ----------
extern "C" void kernel_launch(void* const* d_in, const int* in_sizes, int n_in,
                              void* d_out, int out_size, void* d_ws, size_t ws_size,
                              hipStream_t stream) {
    const float* emb = (const float*)d_in[0];
    const float* Wq  = (const float*)d_in[1];
    const float* bq  = (const float*)d_in[2];
    const float* Wk  = (const float*)d_in[3];
    const float* bk  = (const float*)d_in[4];
    const float* Wv  = (const float*)d_in[5];
    const float* bv  = (const float*)d_in[6];
    float* out = (float*)d_out;

    unsigned short* ws = (unsigned short*)d_ws;
    unsigned short* WtS = ws;                      // 384 KB
    unsigned short* Qb = ws + 192 * 1024;          // 2 MB
    unsigned short* Kb = Qb + QTOT * 64;           // 2 MB
    unsigned short* VT = Kb + QTOT * 64;           // 2 MB  (ends at 6,684,672 B)
    float* accP  = (float*)(VT + QTOT * 64);       // 4 x 4 MB partial acc
    float* lsumP = accP + (size_t)4 * QTOT * 64;   // 4 x 64 KB partial l
    // total ws use ≈ 23.0 MB (round-0 proved ≥ 31.9 MB available)

    prep_weights<<<768, 256, 0, stream>>>(Wq, Wk, Wv, WtS);
    proj_cs<<<512, 256, 0, stream>>>(emb, WtS, bq, bk, bv, Qb, Kb, VT);
    attn32<<<512, 256, 0, stream>>>(Qb, Kb, VT, accP, lsumP);
    finalize<<<1024, 256, 0, stream>>>(accP, lsumP, out);
}

// Round 11
// 154.655 us; speedup vs baseline: 1.1834x; 1.1834x over previous
//
#include <hip/hip_runtime.h>

#define SEQ  4096
#define DMODEL 1024
#define QTOT 16384           // B*S
#define QSCALE 0.18033688011112042f   // (1/sqrt(64)) * log2(e), folded into Q

typedef __bf16 bf16x8 __attribute__((ext_vector_type(8)));
typedef unsigned short u16x8 __attribute__((ext_vector_type(8)));
typedef float f32x4 __attribute__((ext_vector_type(4)));

// ---------- helpers ----------
static __device__ __forceinline__ unsigned short f2bfbits(float f) {
    unsigned int u = __builtin_bit_cast(unsigned int, f);
    unsigned int lsb = (u >> 16) & 1u;
    u += 0x7fffu + lsb;                      // round-to-nearest-even
    return (unsigned short)(u >> 16);
}

static __device__ __forceinline__ bf16x8 ld_frag(const unsigned short* p) {
    uint4 u = *reinterpret_cast<const uint4*>(p);
    return __builtin_bit_cast(bf16x8, u);
}

// ---------- kernel 1: weights -> bf16, pre-swizzled into MFMA fragment order ----------
__global__ void prep_weights(const float* __restrict__ Wq,
                             const float* __restrict__ Wk,
                             const float* __restrict__ Wv,
                             unsigned short* __restrict__ WtS) {
    int o = blockIdx.x * 256 + threadIdx.x;      // 192*1024 total
    int f = o >> 9, q = o & 511;
    int lane = q >> 3, j = q & 7;
    int kc = f / 12, nt = f - kc * 12;
    int n = nt * 16 + (lane & 15);
    int k = kc * 32 + (lane >> 4) * 8 + j;
    float v;
    if (n < 64)       v = Wq[k * 64 + n];
    else if (n < 128) v = Wk[k * 64 + (n - 64)];
    else              v = Wv[k * 64 + (n - 128)];
    WtS[o] = f2bfbits(v);
}

// ---------- kernel 2: QKV projection, coalesced LDS-staged emb ----------
// (round-3 verified kernel, unchanged; row-major Kb / [b][v][t] VT outputs.
//  NOTE: fragment-ordered K/V outputs were bisected on HW in rounds 8/10 and
//  are WRONG despite passing static audit — reverted, do not reintroduce.)
__global__ __launch_bounds__(256) void proj_cs(
        const float* __restrict__ emb, const unsigned short* __restrict__ WtS,
        const float* __restrict__ bq, const float* __restrict__ bk,
        const float* __restrict__ bv,
        unsigned short* __restrict__ Qb, unsigned short* __restrict__ Kb,
        unsigned short* __restrict__ VT) {
    __shared__ __align__(16) unsigned short Et[2][32 * 256];   // 2 x 16 KB

    const int tid = threadIdx.x;
    const int w = tid >> 6, lane = tid & 63;
    const int c = lane & 15, qd = lane >> 4;
    const int m = w & 1, nh = w >> 1;
    const int mbase = blockIdx.x * 32;

    f32x4 acc[6];
#pragma unroll
    for (int i = 0; i < 6; i++) acc[i] = (f32x4){0.f, 0.f, 0.f, 0.f};

    const unsigned short* wpB = WtS + nh * 3072 + lane * 8;

    {
        float4 g[8];
#pragma unroll
        for (int rr = 0; rr < 8; rr++)
            g[rr] = *reinterpret_cast<const float4*>(
                emb + (size_t)(mbase + w * 8 + rr) * DMODEL + lane * 4);
#pragma unroll
        for (int rr = 0; rr < 8; rr++) {
            int row = w * 8 + rr;
            ushort4 p;
            p.x = f2bfbits(g[rr].x); p.y = f2bfbits(g[rr].y);
            p.z = f2bfbits(g[rr].z); p.w = f2bfbits(g[rr].w);
            int off = (lane * 8) ^ ((row & 7) << 4);           // byte off in 512B row
            *reinterpret_cast<ushort4*>(
                reinterpret_cast<char*>(&Et[0][0]) + row * 512 + off) = p;
        }
    }

    bf16x8 wc[6];
#pragma unroll
    for (int jj = 0; jj < 6; jj++) wc[jj] = ld_frag(wpB + jj * 512);

    __syncthreads();

    int cur = 0;
    for (int mega = 0; mega < 4; mega++) {
        float4 g[8];
        if (mega < 3) {
#pragma unroll
            for (int rr = 0; rr < 8; rr++)
                g[rr] = *reinterpret_cast<const float4*>(
                    emb + (size_t)(mbase + w * 8 + rr) * DMODEL
                        + (mega + 1) * 256 + lane * 4);
        }

        const char* Eb = reinterpret_cast<const char*>(&Et[cur][0]);
        bf16x8 aq[8];
#pragma unroll
        for (int ks = 0; ks < 8; ks++) {
            int off = (ks * 64 + qd * 16) ^ ((c & 7) << 4);
            aq[ks] = ld_frag(reinterpret_cast<const unsigned short*>(
                Eb + (m * 16 + c) * 512 + off));
        }

#pragma unroll
        for (int ks = 0; ks < 8; ks++) {
            int s = mega * 8 + ks;
            bf16x8 wn[6];
            if (s < 31) {
#pragma unroll
                for (int jj = 0; jj < 6; jj++)
                    wn[jj] = ld_frag(wpB + (s + 1) * 6144 + jj * 512);
            } else {
#pragma unroll
                for (int jj = 0; jj < 6; jj++) wn[jj] = wc[jj];
            }
#pragma unroll
            for (int jj = 0; jj < 6; jj++)
                acc[jj] = __builtin_amdgcn_mfma_f32_16x16x32_bf16(aq[ks], wc[jj], acc[jj], 0, 0, 0);
#pragma unroll
            for (int jj = 0; jj < 6; jj++) wc[jj] = wn[jj];
        }

        if (mega < 3) {
#pragma unroll
            for (int rr = 0; rr < 8; rr++) {
                int row = w * 8 + rr;
                ushort4 p;
                p.x = f2bfbits(g[rr].x); p.y = f2bfbits(g[rr].y);
                p.z = f2bfbits(g[rr].z); p.w = f2bfbits(g[rr].w);
                int off = (lane * 8) ^ ((row & 7) << 4);
                *reinterpret_cast<ushort4*>(
                    reinterpret_cast<char*>(&Et[cur ^ 1][0]) + row * 512 + off) = p;
            }
        }
        __syncthreads();
        cur ^= 1;
    }

    // ---- epilogue: bias + scale + bf16 store ----
#pragma unroll
    for (int jj = 0; jj < 6; jj++) {
        int n = (nh * 6 + jj) * 16 + c;
        float bias = (n < 64) ? bq[n] : (n < 128) ? bk[n - 64] : bv[n - 128];
        float fac = (n < 64) ? QSCALE : 1.0f;
#pragma unroll
        for (int r = 0; r < 4; r++) {
            int token = mbase + m * 16 + qd * 4 + r;
            unsigned short bits = f2bfbits((acc[jj][r] + bias) * fac);
            if (n < 64)        Qb[(size_t)token * 64 + n] = bits;
            else if (n < 128)  Kb[(size_t)token * 64 + (n - 64)] = bits;
            else {
                int bb = token >> 12, ss = token & 4095;
                VT[((size_t)bb * 64 + (n - 128)) * SEQ + ss] = bits;
            }
        }
    }
}

// ---------- kernel 3: barrier-free flash attention ----------
// round-3 verified body (64 q-rows, grid 256, 8 waves, wave owns a 512-t
// slice) + two scheduling-only edits never yet benched on this body:
//  (1) V-loads hoisted ABOVE the score phase — V is score-independent, so its
//      ~300-500cy L2 latency (x8 iters) hides under QK MFMA + softmax VALU
//      instead of sitting serially before PV (T14; at 2 waves/SIMD ILP is the
//      only latency-hiding available).
//  (2) s_setprio(1) around the MFMA clusters (T5).
// Arithmetic is bit-identical to round 3 (absmax must stay 4.882812e-4).
__global__ __launch_bounds__(512, 2) void attn(
        const unsigned short* __restrict__ Qb, const unsigned short* __restrict__ Kb,
        const unsigned short* __restrict__ VT, float* __restrict__ out) {
    __shared__ __align__(16) unsigned short Pl[8][64 * 72];  // per-wave P [q][t]; aliased as reduce buf
    __shared__ float l_all[8][64];

    const int tid = threadIdx.x;
    const int w = tid >> 6, lane = tid & 63;
    const int c = lane & 15, qd = lane >> 4;
    // XCD pinning: blockIdx%8 = b*2 + (qblk&1)
    const int g3 = blockIdx.x & 7;
    const int b = g3 >> 1;
    const int qblk = ((blockIdx.x >> 3) << 1) | (g3 & 1);
    const int qbase = qblk * 64;
    const int tstart = w * 512;

    // Q A-fragments (same for all 8 waves -> L1 broadcast), pre-scaled by QSCALE
    bf16x8 aq0[4], aq1[4];
#pragma unroll
    for (int qs = 0; qs < 4; qs++) {
        const unsigned short* Qp = Qb + ((size_t)(b << 12) + qbase + qs * 16 + c) * 64 + qd * 8;
        aq0[qs] = ld_frag(Qp);
        aq1[qs] = ld_frag(Qp + 32);
    }

    f32x4 acc[16];                               // [qsub][nt]
#pragma unroll
    for (int i = 0; i < 16; i++) acc[i] = (f32x4){0.f, 0.f, 0.f, 0.f};
    float lsum[4][4];                            // [qsub][r] per-lane partial
#pragma unroll
    for (int qs = 0; qs < 4; qs++)
#pragma unroll
        for (int r = 0; r < 4; r++) lsum[qs][r] = 0.f;

    unsigned short* myP = &Pl[w][0];

#pragma unroll 2
    for (int it = 0; it < 8; it++) {
        const int t0 = tstart + it * 64;
        const unsigned short* Kt = Kb + ((size_t)(b << 12) + t0) * 64;

        // K B-fragments straight from global
        bf16x8 bk0[4], bk1[4];
#pragma unroll
        for (int ts = 0; ts < 4; ts++) {
            bk0[ts] = ld_frag(Kt + (ts * 16 + c) * 64 + qd * 8);
            bk1[ts] = ld_frag(Kt + (ts * 16 + c) * 64 + 32 + qd * 8);
        }
        // V B-fragments issued EARLY (T14): latency hides under QK + softmax
        bf16x8 bv0[4], bv1[4];
#pragma unroll
        for (int nt = 0; nt < 4; nt++) {
            const unsigned short* Vp = VT + (((size_t)b * 64 + nt * 16 + c) << 12) + t0 + qd * 8;
            bv0[nt] = ld_frag(Vp);
            bv1[nt] = ld_frag(Vp + 32);
        }

        // scores -> exp2 -> P into per-wave LDS (no barrier)
#pragma unroll
        for (int qs = 0; qs < 4; qs++) {
            f32x4 sc[4];
            __builtin_amdgcn_s_setprio(1);
#pragma unroll
            for (int ts = 0; ts < 4; ts++) {
                f32x4 z = (f32x4){0.f, 0.f, 0.f, 0.f};
                z = __builtin_amdgcn_mfma_f32_16x16x32_bf16(aq0[qs], bk0[ts], z, 0, 0, 0);
                z = __builtin_amdgcn_mfma_f32_16x16x32_bf16(aq1[qs], bk1[ts], z, 0, 0, 0);
                sc[ts] = z;
            }
            __builtin_amdgcn_s_setprio(0);
#pragma unroll
            for (int ts = 0; ts < 4; ts++)
#pragma unroll
                for (int r = 0; r < 4; r++) {
                    float p = __builtin_amdgcn_exp2f(sc[ts][r]);   // scale folded into Q
                    lsum[qs][r] += p;
                    myP[(qs * 16 + qd * 4 + r) * 72 + ts * 16 + c] = f2bfbits(p);
                }
        }

        // P A-fragments (same-wave LDS readback; compiler inserts lgkmcnt)
#pragma unroll
        for (int qs = 0; qs < 4; qs++) {
            bf16x8 ap0 = ld_frag(&myP[(qs * 16 + c) * 72 + qd * 8]);
            bf16x8 ap1 = ld_frag(&myP[(qs * 16 + c) * 72 + 32 + qd * 8]);
            __builtin_amdgcn_s_setprio(1);
#pragma unroll
            for (int nt = 0; nt < 4; nt++) {
                acc[qs * 4 + nt] = __builtin_amdgcn_mfma_f32_16x16x32_bf16(ap0, bv0[nt], acc[qs * 4 + nt], 0, 0, 0);
                acc[qs * 4 + nt] = __builtin_amdgcn_mfma_f32_16x16x32_bf16(ap1, bv1[nt], acc[qs * 4 + nt], 0, 0, 0);
            }
            __builtin_amdgcn_s_setprio(0);
        }
    }

    // per-wave row-sum reduction across the 16 column lanes
#pragma unroll
    for (int off = 1; off < 16; off <<= 1)
#pragma unroll
        for (int qs = 0; qs < 4; qs++)
#pragma unroll
            for (int r = 0; r < 4; r++) lsum[qs][r] += __shfl_xor(lsum[qs][r], off);
    if (c == 0) {
#pragma unroll
        for (int qs = 0; qs < 4; qs++)
#pragma unroll
            for (int r = 0; r < 4; r++)
                l_all[w][qs * 16 + qd * 4 + r] = lsum[qs][r];
    }

    // tree-reduce acc over 8 waves; reduce buffer aliases Pl (slot = 17408 B)
    float* red = (float*)&Pl[0][0];
    __syncthreads();                              // all main loops + l writes done
    if (w >= 4) {
        float* rp = red + (w - 4) * 4352 + lane * 68;
#pragma unroll
        for (int i = 0; i < 16; i++) *reinterpret_cast<f32x4*>(rp + i * 4) = acc[i];
    }
    __syncthreads();
    if (w < 4) {
        float* rp = red + w * 4352 + lane * 68;
#pragma unroll
        for (int i = 0; i < 16; i++) acc[i] += *reinterpret_cast<const f32x4*>(rp + i * 4);
    }
    __syncthreads();
    if (w == 2 || w == 3) {
        float* rp = red + (w - 2) * 4352 + lane * 68;
#pragma unroll
        for (int i = 0; i < 16; i++) *reinterpret_cast<f32x4*>(rp + i * 4) = acc[i];
    }
    __syncthreads();
    if (w < 2) {
        float* rp = red + w * 4352 + lane * 68;
#pragma unroll
        for (int i = 0; i < 16; i++) acc[i] += *reinterpret_cast<const f32x4*>(rp + i * 4);
    }
    __syncthreads();
    if (w == 1) {
        float* rp = red + lane * 68;
#pragma unroll
        for (int i = 0; i < 16; i++) *reinterpret_cast<f32x4*>(rp + i * 4) = acc[i];
    }
    __syncthreads();
    if (w == 0) {
        float* rp = red + lane * 68;
#pragma unroll
        for (int i = 0; i < 16; i++) acc[i] += *reinterpret_cast<const f32x4*>(rp + i * 4);
#pragma unroll
        for (int qs = 0; qs < 4; qs++)
#pragma unroll
            for (int r = 0; r < 4; r++) {
                int q = qs * 16 + qd * 4 + r;
                float l = 0.f;
#pragma unroll
                for (int ww = 0; ww < 8; ww++) l += l_all[ww][q];
                float inv = 1.0f / l;
                size_t row = (size_t)(b << 12) + qbase + q;
#pragma unroll
                for (int nt = 0; nt < 4; nt++)
                    out[row * 64 + nt * 16 + c] = acc[qs * 4 + nt][r] * inv;
            }
    }
}

// ---------- launch ----------
extern "C" void kernel_launch(void* const* d_in, const int* in_sizes, int n_in,
                              void* d_out, int out_size, void* d_ws, size_t ws_size,
                              hipStream_t stream) {
    const float* emb = (const float*)d_in[0];
    const float* Wq  = (const float*)d_in[1];
    const float* bq  = (const float*)d_in[2];
    const float* Wk  = (const float*)d_in[3];
    const float* bk  = (const float*)d_in[4];
    const float* Wv  = (const float*)d_in[5];
    const float* bv  = (const float*)d_in[6];
    float* out = (float*)d_out;

    unsigned short* ws = (unsigned short*)d_ws;
    unsigned short* WtS = ws;                      // 384 KB
    unsigned short* Qb = ws + 192 * 1024;          // 2 MB
    unsigned short* Kb = Qb + QTOT * 64;           // 2 MB
    unsigned short* VT = Kb + QTOT * 64;           // 2 MB  (total 6,684,672 B)

    prep_weights<<<768, 256, 0, stream>>>(Wq, Wk, Wv, WtS);
    proj_cs<<<512, 256, 0, stream>>>(emb, WtS, bq, bk, bv, Qb, Kb, VT);
    attn<<<256, 512, 0, stream>>>(Qb, Kb, VT, out);
}